// Round 2
// baseline (187.225 us; speedup 1.0000x reference)
//
#include <hip/hip_runtime.h>
#include <hip/hip_bf16.h>
#include <math.h>

// Problem constants (from reference)
#define NN  20000      // nodes
#define NE  50000      // directed edges (undirected -> 2*NE)
#define NE2 100000
#define H   32
#define FN  4
#define FE  2
#define FO  4
#define NL  3

#define FRAGS_PER_LAYER (33 * 2)                   // 33 K-steps (32 weight + 1 bias) x 2 n-tiles
#define BVALS_PER_LAYER (FRAGS_PER_LAYER * 512)    // 33792 bf16 per layer (per hi/lo array)

typedef __attribute__((ext_vector_type(8))) short short8;
typedef __attribute__((ext_vector_type(4))) float f32x4;

__device__ __forceinline__ float gelu_f(float x) {
    // exact GELU: x * 0.5 * (1 + erf(x/sqrt(2)))
    return 0.5f * x * (1.0f + erff(x * 0.7071067811865476f));
}
__device__ __forceinline__ short f2bf(float x) {
    __hip_bfloat16 b = __float2bfloat16(x);
    return __builtin_bit_cast(short, b);
}
__device__ __forceinline__ float bf2f(short s) {
    __hip_bfloat16 b = __builtin_bit_cast(__hip_bfloat16, s);
    return __bfloat162float(b);
}

// ---------------------------------------------------------------------------
// Zero-fill agg (avoid hipMemsetAsync inside graph capture)
// ---------------------------------------------------------------------------
__global__ __launch_bounds__(256) void zero_agg(float4* __restrict__ p) {
    int i = blockIdx.x * 256 + threadIdx.x;
    if (i < NN * H / 4) p[i] = make_float4(0.f, 0.f, 0.f, 0.f);
}

// ---------------------------------------------------------------------------
// Pre-pack W2 (and b2 as a virtual 33rd K-step) into MFMA B-fragment order,
// split into bf16 hi + bf16 lo residual for accuracy.
// Fragment enumeration (must match A-side generation in edge_pass):
//   lane l holds K-slots p = (l>>4)*8 + j, j=0..7;  n-col = nt*16 + (l&15)
//   W2r[kk, o] = w2[kt*1024 + h*32 + o], kk = kt*32 + h; within step: p = h.
// ---------------------------------------------------------------------------
__global__ __launch_bounds__(256) void prep_bfrag(
    const float* __restrict__ eW2, const float* __restrict__ eb2,
    short* __restrict__ Bhi, short* __restrict__ Blo)
{
    int idx = blockIdx.x * 256 + threadIdx.x;
    if (idx >= NL * BVALS_PER_LAYER) return;
    int layer = idx / BVALS_PER_LAYER;
    int rem   = idx - layer * BVALS_PER_LAYER;
    int f      = rem >> 9;          // frag id 0..65
    int within = rem & 511;         // l*8 + j
    int step = f >> 1, nt = f & 1;
    int l = within >> 3, j = within & 7;
    int p = ((l >> 4) << 3) + j;    // K-slot within step (0..31) == h index
    int n = nt * 16 + (l & 15);     // output column (0..31)
    float v;
    if (step < 32) v = eW2[layer * 32768 + step * 1024 + p * 32 + n];
    else           v = eb2[layer * 1024 + p * 32 + n];
    short hi = f2bf(v);
    short lo = f2bf(v - bf2f(hi));
    Bhi[idx] = hi;
    Blo[idx] = lo;
}

// ---------------------------------------------------------------------------
// Input encoder: h = x@W_in + b_in + gelu(pm@mW1+mb1)@mW2 + mb2   (f32)
// ---------------------------------------------------------------------------
__global__ __launch_bounds__(256) void encoder(
    const float* __restrict__ x, const float* __restrict__ pm,
    const float* __restrict__ W_in, const float* __restrict__ b_in,
    const float* __restrict__ mW1, const float* __restrict__ mb1,
    const float* __restrict__ mW2, const float* __restrict__ mb2,
    float* __restrict__ h)
{
    __shared__ float sWin[FN*H], sW1[FN*H], sW2[H*H];
    __shared__ float sbin[H], sb1[H], sb2[H];
    int tid = threadIdx.x;
    for (int i = tid; i < FN*H; i += 256) { sWin[i] = W_in[i]; sW1[i] = mW1[i]; }
    for (int i = tid; i < H*H; i += 256) sW2[i] = mW2[i];
    if (tid < H) { sbin[tid] = b_in[tid]; sb1[tid] = mb1[tid]; sb2[tid] = mb2[tid]; }
    __syncthreads();
    int n = blockIdx.x * 256 + tid;
    if (n >= NN) return;
    float xv[FN], pv[FN];
#pragma unroll
    for (int i = 0; i < FN; ++i) { xv[i] = x[n*FN+i]; pv[i] = pm[n*FN+i]; }
    float m[H];
#pragma unroll
    for (int j = 0; j < H; ++j) {
        float a = sb1[j];
#pragma unroll
        for (int i = 0; i < FN; ++i) a += pv[i] * sW1[i*H+j];
        m[j] = gelu_f(a);
    }
#pragma unroll
    for (int j = 0; j < H; ++j) {
        float a = sbin[j] + sb2[j];
#pragma unroll
        for (int i = 0; i < FN; ++i) a += xv[i] * sWin[i*H+j];
        float s = 0.f;
#pragma unroll
        for (int k = 0; k < H; ++k) s += m[k] * sW2[k*H+j];
        h[n*H+j] = a + s;
    }
}

// ---------------------------------------------------------------------------
// Edge pass: one wave per block, 64 edges per wave (4 MFMA M-tiles).
// msg[64,32] = U[64,1024+32bias] @ W2r  via mfma_f32_16x16x32_bf16 (hi+lo),
// then atomicAdd scatter into agg[dst].
// ---------------------------------------------------------------------------
__global__ __launch_bounds__(64) void edge_pass(
    const float* __restrict__ h,
    const int* __restrict__ ei,           // [2, NE] int32 (harness converts int64 -> int32)
    const float* __restrict__ ea,         // [NE, 2]
    const float* __restrict__ w1,         // [2, 32]
    const float* __restrict__ b1,         // [32]
    const short* __restrict__ Bhi,        // layer-offset bf16 fragments
    const short* __restrict__ Blo,
    float* __restrict__ agg)              // [NN, 32]
{
    __shared__ float t_lds[32 * 64];      // [step][edge-in-block], transposed
    __shared__ int src_lds[64], dst_lds[64];

    int tid = threadIdx.x;
    int eb  = blockIdx.x * 64;
    {
        int e = eb + tid;
        bool v = e < NE2;
        int er = v ? (e < NE ? e : e - NE) : 0;
        int s, d;
        if (v && e >= NE) { s = ei[NE + er]; d = ei[er]; }
        else              { s = ei[er];      d = ei[NE + er]; }
        if (!v) { s = 0; d = 0; }
        src_lds[tid] = s; dst_lds[tid] = d;
        float a0 = v ? ea[er*2]   : 0.f;
        float a1 = v ? ea[er*2+1] : 0.f;
        for (int k = 0; k < 32; ++k) {
            float tv = v ? gelu_f(a0 * w1[k] + a1 * w1[32+k] + b1[k]) : 0.f;
            t_lds[k*64 + tid] = tv;
        }
    }
    __syncthreads();

    int lg = tid >> 4, lm = tid & 15;

    // Per-lane h[src] slice: 8 features (k-slots) for each of 4 M-tile edges.
    float hs[4][8];
#pragma unroll
    for (int m = 0; m < 4; ++m) {
        int s = src_lds[m*16 + lm];
        const float4* hp = (const float4*)(h + s*H + lg*8);
        float4 u0 = hp[0], u1 = hp[1];
        hs[m][0]=u0.x; hs[m][1]=u0.y; hs[m][2]=u0.z; hs[m][3]=u0.w;
        hs[m][4]=u1.x; hs[m][5]=u1.y; hs[m][6]=u1.z; hs[m][7]=u1.w;
    }

    f32x4 acc[4][2];
#pragma unroll
    for (int m = 0; m < 4; ++m) {
        acc[m][0] = (f32x4){0.f,0.f,0.f,0.f};
        acc[m][1] = (f32x4){0.f,0.f,0.f,0.f};
    }

    const short8* Bh = (const short8*)Bhi;   // 64 short8 per fragment
    const short8* Bl = (const short8*)Blo;
    short8 cb0h = Bh[tid], cb1h = Bh[64 + tid];
    short8 cb0l = Bl[tid], cb1l = Bl[64 + tid];
    short8 nb0h = cb0h, nb1h = cb1h, nb0l = cb0l, nb1l = cb1l;

#pragma unroll 1
    for (int step = 0; step < 33; ++step) {
        if (step < 32) {                      // prefetch next step's B frags
            int fo = (step + 1) * 128 + tid;  // (step+1)*2 frags * 64
            nb0h = Bh[fo]; nb1h = Bh[fo + 64];
            nb0l = Bl[fo]; nb1l = Bl[fo + 64];
        }
#pragma unroll
        for (int m = 0; m < 4; ++m) {
            float tv = (step < 32) ? t_lds[step*64 + m*16 + lm] : 1.0f;
            short8 a;
#pragma unroll
            for (int j = 0; j < 8; ++j) a[j] = f2bf(tv * hs[m][j]);
            acc[m][0] = __builtin_amdgcn_mfma_f32_16x16x32_bf16(a, cb0h, acc[m][0], 0, 0, 0);
            acc[m][0] = __builtin_amdgcn_mfma_f32_16x16x32_bf16(a, cb0l, acc[m][0], 0, 0, 0);
            acc[m][1] = __builtin_amdgcn_mfma_f32_16x16x32_bf16(a, cb1h, acc[m][1], 0, 0, 0);
            acc[m][1] = __builtin_amdgcn_mfma_f32_16x16x32_bf16(a, cb1l, acc[m][1], 0, 0, 0);
        }
        cb0h = nb0h; cb1h = nb1h; cb0l = nb0l; cb1l = nb1l;
    }

    // C/D layout (HW-verified): col = lane&15, row = (lane>>4)*4 + reg
#pragma unroll
    for (int m = 0; m < 4; ++m) {
#pragma unroll
        for (int r = 0; r < 4; ++r) {
            int erow = m*16 + lg*4 + r;
            if (eb + erow < NE2) {
                int d = dst_lds[erow];
                atomicAdd(agg + d*H + lm,      acc[m][0][r]);
                atomicAdd(agg + d*H + 16 + lm, acc[m][1][r]);
            }
        }
    }
}

// ---------------------------------------------------------------------------
// Node update: hc = agg + h@Wr + cb; LayerNorm; h += gelu(hn)   (f32)
// ---------------------------------------------------------------------------
__global__ __launch_bounds__(256) void node_update(
    float* __restrict__ h, const float* __restrict__ agg,
    const float* __restrict__ wr, const float* __restrict__ cb,
    const float* __restrict__ gamma, const float* __restrict__ beta)
{
    __shared__ float swr[H*H];
    __shared__ float scb[H], sg[H], sb[H];
    int tid = threadIdx.x;
    for (int i = tid; i < H*H; i += 256) swr[i] = wr[i];
    if (tid < H) { scb[tid] = cb[tid]; sg[tid] = gamma[tid]; sb[tid] = beta[tid]; }
    __syncthreads();
    int n = blockIdx.x * 256 + tid;
    if (n >= NN) return;

    float hv[H], hc[H];
#pragma unroll
    for (int q = 0; q < 8; ++q) {
        float4 v = ((const float4*)(h + n*H))[q];
        hv[q*4+0]=v.x; hv[q*4+1]=v.y; hv[q*4+2]=v.z; hv[q*4+3]=v.w;
        float4 g = ((const float4*)(agg + n*H))[q];
        hc[q*4+0]=g.x; hc[q*4+1]=g.y; hc[q*4+2]=g.z; hc[q*4+3]=g.w;
    }
#pragma unroll
    for (int o = 0; o < H; ++o) hc[o] += scb[o];
#pragma unroll
    for (int k = 0; k < H; ++k) {
        float hk = hv[k];
#pragma unroll
        for (int o = 0; o < H; ++o) hc[o] += hk * swr[k*H+o];
    }
    float mu = 0.f;
#pragma unroll
    for (int o = 0; o < H; ++o) mu += hc[o];
    mu *= (1.0f/H);
    float var = 0.f;
#pragma unroll
    for (int o = 0; o < H; ++o) { float d = hc[o]-mu; var += d*d; }
    var *= (1.0f/H);
    float rs = rsqrtf(var + 1e-5f);
#pragma unroll
    for (int o = 0; o < H; ++o) {
        float hn = (hc[o]-mu)*rs*sg[o] + sb[o];
        hv[o] += gelu_f(hn);
    }
#pragma unroll
    for (int q = 0; q < 8; ++q) {
        float4 v = make_float4(hv[q*4+0], hv[q*4+1], hv[q*4+2], hv[q*4+3]);
        ((float4*)(h + n*H))[q] = v;
    }
}

// ---------------------------------------------------------------------------
// Decoder: out = gelu(h@dW1+db1)@dW2 + db2   (f32)
// ---------------------------------------------------------------------------
__global__ __launch_bounds__(256) void decoder(
    const float* __restrict__ h,
    const float* __restrict__ dW1, const float* __restrict__ db1,
    const float* __restrict__ dW2, const float* __restrict__ db2,
    float* __restrict__ out)
{
    __shared__ float sW1[H*H], sW2[H*FO];
    __shared__ float sb1[H], sb2[FO];
    int tid = threadIdx.x;
    for (int i = tid; i < H*H; i += 256) sW1[i] = dW1[i];
    for (int i = tid; i < H*FO; i += 256) sW2[i] = dW2[i];
    if (tid < H) sb1[tid] = db1[tid];
    if (tid < FO) sb2[tid] = db2[tid];
    __syncthreads();
    int n = blockIdx.x * 256 + tid;
    if (n >= NN) return;
    float hv[H];
#pragma unroll
    for (int q = 0; q < 8; ++q) {
        float4 v = ((const float4*)(h + n*H))[q];
        hv[q*4+0]=v.x; hv[q*4+1]=v.y; hv[q*4+2]=v.z; hv[q*4+3]=v.w;
    }
    float g[H];
#pragma unroll
    for (int j = 0; j < H; ++j) {
        float a = sb1[j];
#pragma unroll
        for (int k = 0; k < H; ++k) a += hv[k] * sW1[k*H+j];
        g[j] = gelu_f(a);
    }
#pragma unroll
    for (int o = 0; o < FO; ++o) {
        float a = sb2[o];
#pragma unroll
        for (int k = 0; k < H; ++k) a += g[k] * sW2[k*FO+o];
        out[n*FO+o] = a;
    }
}

// ---------------------------------------------------------------------------
extern "C" void kernel_launch(void* const* d_in, const int* in_sizes, int n_in,
                              void* d_out, int out_size, void* d_ws, size_t ws_size,
                              hipStream_t stream)
{
    const float* x    = (const float*)d_in[0];
    const float* pm   = (const float*)d_in[1];
    const int*   ei   = (const int*)d_in[2];      // int inputs arrive as int32
    const float* ea   = (const float*)d_in[3];
    const float* W_in = (const float*)d_in[4];
    const float* b_in = (const float*)d_in[5];
    const float* mW1  = (const float*)d_in[6];
    const float* mb1  = (const float*)d_in[7];
    const float* mW2  = (const float*)d_in[8];
    const float* mb2  = (const float*)d_in[9];
    const float* eW1  = (const float*)d_in[10];
    const float* eb1  = (const float*)d_in[11];
    const float* eW2  = (const float*)d_in[12];
    const float* eb2  = (const float*)d_in[13];
    const float* Wr   = (const float*)d_in[14];
    const float* cb   = (const float*)d_in[15];
    const float* gm   = (const float*)d_in[16];
    const float* bt   = (const float*)d_in[17];
    const float* dW1  = (const float*)d_in[18];
    const float* db1  = (const float*)d_in[19];
    const float* dW2  = (const float*)d_in[20];
    const float* db2  = (const float*)d_in[21];
    float* out = (float*)d_out;

    float* h   = (float*)d_ws;                 // NN*H f32
    float* agg = h + NN*H;                     // NN*H f32
    short* Bhi = (short*)(agg + NN*H);         // NL * 33792 bf16
    short* Blo = Bhi + NL * BVALS_PER_LAYER;   // NL * 33792 bf16

    prep_bfrag<<<(NL*BVALS_PER_LAYER + 255)/256, 256, 0, stream>>>(eW2, eb2, Bhi, Blo);
    encoder<<<(NN + 255)/256, 256, 0, stream>>>(x, pm, W_in, b_in, mW1, mb1, mW2, mb2, h);

    for (int l = 0; l < NL; ++l) {
        zero_agg<<<(NN*H/4 + 255)/256, 256, 0, stream>>>((float4*)agg);
        edge_pass<<<(NE2 + 63)/64, 64, 0, stream>>>(
            h, ei, ea, eW1 + l*FE*H, eb1 + l*H,
            Bhi + l*BVALS_PER_LAYER, Blo + l*BVALS_PER_LAYER, agg);
        node_update<<<(NN + 255)/256, 256, 0, stream>>>(
            h, agg, Wr + l*H*H, cb + l*H, gm + l*H, bt + l*H);
    }

    decoder<<<(NN + 255)/256, 256, 0, stream>>>(h, dW1, db1, dW2, db2, out);
}

// Round 3
// 181.099 us; speedup vs baseline: 1.0338x; 1.0338x over previous
//
#include <hip/hip_runtime.h>
#include <hip/hip_bf16.h>
#include <math.h>

// Problem constants (from reference)
#define NN  20000      // nodes
#define NE  50000      // directed edges (undirected -> 2*NE)
#define NE2 100000
#define H   32
#define FN  4
#define FE  2
#define FO  4
#define NL  3

#define FRAGS_PER_LAYER (33 * 2)                   // 33 K-steps x 2 n-tiles
#define BVALS_PER_LAYER (FRAGS_PER_LAYER * 512)    // 33792 bf16 per layer (per hi/lo array)

#define TCHUNKS 196                                 // ceil(NE/256)
#define NB_TALL (NL * 32 * TCHUNKS)                 // 18816
#define NB_PREP ((NL * BVALS_PER_LAYER + 255)/256)  // 396
#define NB_ZERO (NN * H / 4 / 256)                  // 625
#define NB_ENC  ((NN + 255)/256)                    // 79

typedef __attribute__((ext_vector_type(8))) short short8;
typedef __attribute__((ext_vector_type(4))) float f32x4;

__device__ __forceinline__ float gelu_f(float x) {
    return 0.5f * x * (1.0f + erff(x * 0.7071067811865476f));
}
__device__ __forceinline__ short f2bf(float x) {
    __hip_bfloat16 b = __float2bfloat16(x);
    return __builtin_bit_cast(short, b);
}
__device__ __forceinline__ float bf2f(short s) {
    __hip_bfloat16 b = __builtin_bit_cast(__hip_bfloat16, s);
    return __bfloat162float(b);
}

// ---------------------------------------------------------------------------
// Fused prologue: [t_all | prep_bfrag | zero_agg | encoder] by blockIdx range.
// ---------------------------------------------------------------------------
__global__ __launch_bounds__(256) void prologue(
    const float* __restrict__ x, const float* __restrict__ pm,
    const float* __restrict__ W_in, const float* __restrict__ b_in,
    const float* __restrict__ mW1, const float* __restrict__ mb1,
    const float* __restrict__ mW2, const float* __restrict__ mb2,
    const float* __restrict__ eW1, const float* __restrict__ eb1,
    const float* __restrict__ eW2, const float* __restrict__ eb2,
    const float* __restrict__ ea,
    float* __restrict__ h, float* __restrict__ agg,
    short* __restrict__ Bhi, short* __restrict__ Blo,
    float* __restrict__ tfull)
{
    int bid = blockIdx.x;
    int tid = threadIdx.x;

    if (bid < NB_TALL) {
        // ---- t_all: t[l][k][er] = gelu(ea[er,0]*w1[l,0,k] + ea[er,1]*w1[l,1,k] + b1[l,k])
        int l     = bid / (32 * TCHUNKS);
        int rem   = bid - l * 32 * TCHUNKS;
        int k     = rem / TCHUNKS;
        int chunk = rem - k * TCHUNKS;
        int er    = chunk * 256 + tid;
        float w0 = eW1[l*FE*H + k];
        float w1 = eW1[l*FE*H + H + k];
        float bb = eb1[l*H + k];
        if (er < NE) {
            float tv = gelu_f(ea[er*2] * w0 + ea[er*2+1] * w1 + bb);
            tfull[(l*32 + k) * NE + er] = tv;
        }
        return;
    }
    bid -= NB_TALL;

    if (bid < NB_PREP) {
        // ---- prep_bfrag: W2 (+b2 as 33rd step) -> MFMA B-fragment order, hi+lo
        int idx = bid * 256 + tid;
        if (idx >= NL * BVALS_PER_LAYER) return;
        int layer = idx / BVALS_PER_LAYER;
        int rem   = idx - layer * BVALS_PER_LAYER;
        int f      = rem >> 9;
        int within = rem & 511;
        int step = f >> 1, nt = f & 1;
        int l = within >> 3, j = within & 7;
        int p = ((l >> 4) << 3) + j;
        int n = nt * 16 + (l & 15);
        float v;
        if (step < 32) v = eW2[layer * 32768 + step * 1024 + p * 32 + n];
        else           v = eb2[layer * 1024 + p * 32 + n];
        short hi = f2bf(v);
        short lo = f2bf(v - bf2f(hi));
        Bhi[idx] = hi;
        Blo[idx] = lo;
        return;
    }
    bid -= NB_PREP;

    if (bid < NB_ZERO) {
        // ---- zero agg (for layer 0)
        int i = bid * 256 + tid;
        ((float4*)agg)[i] = make_float4(0.f, 0.f, 0.f, 0.f);
        return;
    }
    bid -= NB_ZERO;

    // ---- encoder: h = x@W_in + b_in + gelu(pm@mW1+mb1)@mW2 + mb2
    __shared__ float sWin[FN*H], sW1[FN*H], sW2[H*H];
    __shared__ float sbin[H], sb1[H], sb2[H];
    for (int i = tid; i < FN*H; i += 256) { sWin[i] = W_in[i]; sW1[i] = mW1[i]; }
    for (int i = tid; i < H*H; i += 256) sW2[i] = mW2[i];
    if (tid < H) { sbin[tid] = b_in[tid]; sb1[tid] = mb1[tid]; sb2[tid] = mb2[tid]; }
    __syncthreads();
    int n = bid * 256 + tid;
    if (n >= NN) return;
    float xv[FN], pv[FN];
#pragma unroll
    for (int i = 0; i < FN; ++i) { xv[i] = x[n*FN+i]; pv[i] = pm[n*FN+i]; }
    float m[H];
#pragma unroll
    for (int j = 0; j < H; ++j) {
        float a = sb1[j];
#pragma unroll
        for (int i = 0; i < FN; ++i) a += pv[i] * sW1[i*H+j];
        m[j] = gelu_f(a);
    }
#pragma unroll
    for (int j = 0; j < H; ++j) {
        float a = sbin[j] + sb2[j];
#pragma unroll
        for (int i = 0; i < FN; ++i) a += xv[i] * sWin[i*H+j];
        float s = 0.f;
#pragma unroll
        for (int k = 0; k < H; ++k) s += m[k] * sW2[k*H+j];
        h[n*H+j] = a + s;
    }
}

// ---------------------------------------------------------------------------
// Edge pass: 256 threads = 4 waves, 64 edges per wave (4 MFMA M-tiles each).
// Grid: 2*TCHUNKS blocks; first half = forward edges, second half = reversed.
// msg[64,32] = U[64,1024+32bias] @ W2r via mfma_f32_16x16x32_bf16 (hi+lo),
// then atomicAdd scatter into agg[dst].
// ---------------------------------------------------------------------------
__global__ __launch_bounds__(256) void edge_pass(
    const float* __restrict__ h,
    const int* __restrict__ ei,           // [2, NE] int32
    const float* __restrict__ tfull_l,    // [32][NE] precomputed t for this layer
    const short* __restrict__ Bhi,
    const short* __restrict__ Blo,
    float* __restrict__ agg)              // [NN, 32]
{
    __shared__ float t_lds[32][256];      // [k][block-local edge]
    __shared__ int src_lds[256], dst_lds[256];

    int tid = threadIdx.x;
    int bid = blockIdx.x;
    bool half2 = bid >= TCHUNKS;
    int er_base = (half2 ? bid - TCHUNKS : bid) * 256;

    {   // src/dst for this block's 256 edges
        int er = er_base + tid;
        int erc = er < NE ? er : NE - 1;
        int s, d;
        if (half2) { s = ei[NE + erc]; d = ei[erc]; }
        else       { s = ei[erc];      d = ei[NE + erc]; }
        bool v = er < NE;
        src_lds[tid] = v ? s : 0;
        dst_lds[tid] = v ? d : 0;
    }
    {   // stage t tile: 32 k-rows x 256 edges (coalesced float4)
        int c  = tid & 63;      // float4 column
        int kq = tid >> 6;      // 0..3
        int col = er_base + c * 4;
        if (col > NE - 4) col = NE - 4;   // NE%4==0: never corrupts valid edges
#pragma unroll
        for (int q = 0; q < 8; ++q) {
            int k = q * 4 + kq;
            float4 tv = *(const float4*)(tfull_l + k * NE + col);
            *(float4*)&t_lds[k][c * 4] = tv;
        }
    }
    __syncthreads();

    int wv = tid >> 6, lane = tid & 63;
    int lg = lane >> 4, lm = lane & 15;
    int jbase = wv * 64;

    // Per-lane h[src] slice: 8 features (k-slots) for each of 4 M-tile edges.
    float hs[4][8];
#pragma unroll
    for (int m = 0; m < 4; ++m) {
        int s = src_lds[jbase + m*16 + lm];
        const float4* hp = (const float4*)(h + s*H + lg*8);
        float4 u0 = hp[0], u1 = hp[1];
        hs[m][0]=u0.x; hs[m][1]=u0.y; hs[m][2]=u0.z; hs[m][3]=u0.w;
        hs[m][4]=u1.x; hs[m][5]=u1.y; hs[m][6]=u1.z; hs[m][7]=u1.w;
    }

    f32x4 acc[4][2];
#pragma unroll
    for (int m = 0; m < 4; ++m) {
        acc[m][0] = (f32x4){0.f,0.f,0.f,0.f};
        acc[m][1] = (f32x4){0.f,0.f,0.f,0.f};
    }

    const short8* Bh = (const short8*)Bhi;   // 64 short8 per fragment
    const short8* Bl = (const short8*)Blo;
    short8 cb0h = Bh[lane], cb1h = Bh[64 + lane];
    short8 cb0l = Bl[lane], cb1l = Bl[64 + lane];
    short8 nb0h = cb0h, nb1h = cb1h, nb0l = cb0l, nb1l = cb1l;

#pragma unroll 1
    for (int step = 0; step < 33; ++step) {
        if (step < 32) {                      // prefetch next step's B frags
            int fo = (step + 1) * 128 + lane;
            nb0h = Bh[fo]; nb1h = Bh[fo + 64];
            nb0l = Bl[fo]; nb1l = Bl[fo + 64];
        }
#pragma unroll
        for (int m = 0; m < 4; ++m) {
            float tv = (step < 32) ? t_lds[step][jbase + m*16 + lm] : 1.0f;
            short8 a;
#pragma unroll
            for (int j = 0; j < 8; ++j) a[j] = f2bf(tv * hs[m][j]);
            acc[m][0] = __builtin_amdgcn_mfma_f32_16x16x32_bf16(a, cb0h, acc[m][0], 0, 0, 0);
            acc[m][0] = __builtin_amdgcn_mfma_f32_16x16x32_bf16(a, cb0l, acc[m][0], 0, 0, 0);
            acc[m][1] = __builtin_amdgcn_mfma_f32_16x16x32_bf16(a, cb1h, acc[m][1], 0, 0, 0);
            acc[m][1] = __builtin_amdgcn_mfma_f32_16x16x32_bf16(a, cb1l, acc[m][1], 0, 0, 0);
        }
        cb0h = nb0h; cb1h = nb1h; cb0l = nb0l; cb1l = nb1l;
    }

    // C/D layout: col = lane&15, row = (lane>>4)*4 + reg
#pragma unroll
    for (int m = 0; m < 4; ++m) {
#pragma unroll
        for (int r = 0; r < 4; ++r) {
            int erow = jbase + m*16 + lg*4 + r;
            if (er_base + erow < NE) {
                int d = dst_lds[erow];
                atomicAdd(agg + d*H + lm,      acc[m][0][r]);
                atomicAdd(agg + d*H + 16 + lm, acc[m][1][r]);
            }
        }
    }
}

// ---------------------------------------------------------------------------
// Node update: hc = agg + h@Wr + cb; LayerNorm; h += gelu(hn).
// Non-last: writes h, re-zeros agg for next layer.
// Last: fuses decoder, writes out.
// ---------------------------------------------------------------------------
__global__ __launch_bounds__(256) void node_update(
    float* __restrict__ h, float* __restrict__ agg,
    const float* __restrict__ wr, const float* __restrict__ cb,
    const float* __restrict__ gamma, const float* __restrict__ beta,
    const float* __restrict__ dW1, const float* __restrict__ db1,
    const float* __restrict__ dW2, const float* __restrict__ db2,
    float* __restrict__ out, int last)
{
    __shared__ float swr[H*H], sW1d[H*H], sW2d[H*FO];
    __shared__ float scb[H], sg[H], sb[H], sb1d[H], sb2d[FO];
    int tid = threadIdx.x;
    for (int i = tid; i < H*H; i += 256) { swr[i] = wr[i]; sW1d[i] = dW1[i]; }
    for (int i = tid; i < H*FO; i += 256) sW2d[i] = dW2[i];
    if (tid < H) { scb[tid] = cb[tid]; sg[tid] = gamma[tid]; sb[tid] = beta[tid]; sb1d[tid] = db1[tid]; }
    if (tid < FO) sb2d[tid] = db2[tid];
    __syncthreads();
    int n = blockIdx.x * 256 + tid;
    if (n >= NN) return;

    float hv[H], hc[H];
#pragma unroll
    for (int q = 0; q < 8; ++q) {
        float4 v = ((const float4*)(h + n*H))[q];
        hv[q*4+0]=v.x; hv[q*4+1]=v.y; hv[q*4+2]=v.z; hv[q*4+3]=v.w;
        float4 g = ((const float4*)(agg + n*H))[q];
        hc[q*4+0]=g.x; hc[q*4+1]=g.y; hc[q*4+2]=g.z; hc[q*4+3]=g.w;
    }
#pragma unroll
    for (int o = 0; o < H; ++o) hc[o] += scb[o];
#pragma unroll
    for (int k = 0; k < H; ++k) {
        float hk = hv[k];
#pragma unroll
        for (int o = 0; o < H; ++o) hc[o] += hk * swr[k*H+o];
    }
    float mu = 0.f;
#pragma unroll
    for (int o = 0; o < H; ++o) mu += hc[o];
    mu *= (1.0f/H);
    float var = 0.f;
#pragma unroll
    for (int o = 0; o < H; ++o) { float d = hc[o]-mu; var += d*d; }
    var *= (1.0f/H);
    float rs = rsqrtf(var + 1e-5f);
#pragma unroll
    for (int o = 0; o < H; ++o) {
        float hn = (hc[o]-mu)*rs*sg[o] + sb[o];
        hv[o] += gelu_f(hn);
    }

    if (!last) {
#pragma unroll
        for (int q = 0; q < 8; ++q) {
            ((float4*)(h + n*H))[q]   = make_float4(hv[q*4+0], hv[q*4+1], hv[q*4+2], hv[q*4+3]);
            ((float4*)(agg + n*H))[q] = make_float4(0.f, 0.f, 0.f, 0.f);
        }
    } else {
        // fused decoder: out = gelu(hv@dW1+db1)@dW2 + db2
        float g[H];
#pragma unroll
        for (int j = 0; j < H; ++j) {
            float a = sb1d[j];
#pragma unroll
            for (int k = 0; k < H; ++k) a += hv[k] * sW1d[k*H+j];
            g[j] = gelu_f(a);
        }
#pragma unroll
        for (int o = 0; o < FO; ++o) {
            float a = sb2d[o];
#pragma unroll
            for (int k = 0; k < H; ++k) a += g[k] * sW2d[k*FO+o];
            out[n*FO+o] = a;
        }
    }
}

// ---------------------------------------------------------------------------
extern "C" void kernel_launch(void* const* d_in, const int* in_sizes, int n_in,
                              void* d_out, int out_size, void* d_ws, size_t ws_size,
                              hipStream_t stream)
{
    const float* x    = (const float*)d_in[0];
    const float* pm   = (const float*)d_in[1];
    const int*   ei   = (const int*)d_in[2];      // int inputs arrive as int32
    const float* ea   = (const float*)d_in[3];
    const float* W_in = (const float*)d_in[4];
    const float* b_in = (const float*)d_in[5];
    const float* mW1  = (const float*)d_in[6];
    const float* mb1  = (const float*)d_in[7];
    const float* mW2  = (const float*)d_in[8];
    const float* mb2  = (const float*)d_in[9];
    const float* eW1  = (const float*)d_in[10];
    const float* eb1  = (const float*)d_in[11];
    const float* eW2  = (const float*)d_in[12];
    const float* eb2  = (const float*)d_in[13];
    const float* Wr   = (const float*)d_in[14];
    const float* cb   = (const float*)d_in[15];
    const float* gm   = (const float*)d_in[16];
    const float* bt   = (const float*)d_in[17];
    const float* dW1  = (const float*)d_in[18];
    const float* db1  = (const float*)d_in[19];
    const float* dW2  = (const float*)d_in[20];
    const float* db2  = (const float*)d_in[21];
    float* out = (float*)d_out;

    float* h     = (float*)d_ws;                  // NN*H f32
    float* agg   = h + NN*H;                      // NN*H f32
    float* tfull = agg + NN*H;                    // NL*32*NE f32
    short* Bhi   = (short*)(tfull + NL*32*NE);    // NL*33792 bf16
    short* Blo   = Bhi + NL * BVALS_PER_LAYER;    // NL*33792 bf16

    prologue<<<NB_TALL + NB_PREP + NB_ZERO + NB_ENC, 256, 0, stream>>>(
        x, pm, W_in, b_in, mW1, mb1, mW2, mb2, eW1, eb1, eW2, eb2, ea,
        h, agg, Bhi, Blo, tfull);

    for (int l = 0; l < NL; ++l) {
        edge_pass<<<2*TCHUNKS, 256, 0, stream>>>(
            h, ei, tfull + l*32*NE,
            Bhi + l*BVALS_PER_LAYER, Blo + l*BVALS_PER_LAYER, agg);
        node_update<<<(NN + 255)/256, 256, 0, stream>>>(
            h, agg, Wr + l*H*H, cb + l*H, gm + l*H, bt + l*H,
            dW1, db1, dW2, db2, out, l == NL-1);
    }
}